// Round 6
// baseline (196.997 us; speedup 1.0000x reference)
//
#include <hip/hip_runtime.h>

// Shapes: B=4, NH=8, DIM=32, WS=8, WA=64, H=W=128, PLANE=16384.
// qkv:(4,8,96,128,128)f32  ch:(4,256,128,128)f32  lsc:(8)  btab:(225,8)
// pw:(256,256)  pb:(256)  ridx:(64,64)i32  out:(4,256,128,128)f32
//
// ws: biasG f32 [8][64][64] @0 (128 KB); wbf bf16 [256][256] @128K (128 KB)

typedef __attribute__((ext_vector_type(8))) short short8v;
typedef __attribute__((ext_vector_type(4))) float f32x4;
typedef __attribute__((ext_vector_type(2))) unsigned int u32x2;

#define PLANE 16384
#define LOG100 4.6051701859880914f

static __device__ __forceinline__ unsigned short f2bf(float x) {
  union { float f; unsigned u; } v; v.f = x;
  unsigned r = v.u + 0x7fff + ((v.u >> 16) & 1);
  return (unsigned short)(r >> 16);
}
static __device__ __forceinline__ float bf2f(unsigned short b) {
  union { unsigned u; float f; } v; v.u = ((unsigned)b) << 16;
  return v.f;
}

__global__ __launch_bounds__(256) void prep_kernel(
    const float* __restrict__ btab, const int* __restrict__ ridx,
    const float* __restrict__ pw, float* __restrict__ biasG,
    unsigned int* __restrict__ wbf)
{
  const int blk = blockIdx.x, tid = threadIdx.x;
  if (blk < 128) {                      // biasG[h][q][k]
    int i = blk * 256 + tid;
    int h = i >> 12, qk = i & 4095;
    biasG[i] = btab[ridx[qk] * 8 + h];
  } else {                              // w -> bf16 packed pairs
    int i = (blk - 128) * 256 + tid;
    wbf[i] = (unsigned)f2bf(pw[2 * i]) | ((unsigned)f2bf(pw[2 * i + 1]) << 16);
  }
}

// block = window-pair: 512 blocks x 1024 threads (16 waves).
// wave = (h = wv&7, win = wv>>3). Two barriers total.
// LDS: x_lds bf16 [128 pos][256 c] swizzled @0 (64KB); chm f32 [32][132] @64K.
__global__ __launch_bounds__(1024, 4) void fused_kernel(
    const float* __restrict__ qkv, const float* __restrict__ ch,
    const float* __restrict__ lsc, const float* __restrict__ biasG,
    const unsigned short* __restrict__ wbf, const float* __restrict__ pb,
    float* __restrict__ out)
{
  __shared__ __align__(16) char smem[82432];
  float* chm = (float*)(smem + 65536);       // [32][132] f32

  const int tid = threadIdx.x;
  int bid = blockIdx.x;
  bid = (bid & 7) * 64 + (bid >> 3);         // XCD swizzle (512 = 8*64)
  const int b   = bid >> 7;
  const int wy  = (bid >> 3) & 15;
  const int wxp = bid & 7;
  const int y0  = wy << 3, x0 = wxp << 4;

  const int wv = tid >> 6, lane = tid & 63;
  const int lg = lane >> 4, lr = lane & 15;
  const int h = wv & 7, win = wv >> 3;
  const int xw = x0 + win * 8;

  const size_t qbase = ((size_t)((b * 8 + h) * 96)) * PLANE;
  const float* qg = qkv + qbase;
  const float* kg = qg + (size_t)32 * PLANE;
  const float* vg = qg + (size_t)64 * PLANE;

  // ================= phase 0: ISSUE ALL per-wave global loads =================
  // V raw (8 x float4)
  float4 vA[2][2], vB[2][2];
#pragma unroll
  for (int dt = 0; dt < 2; ++dt) {
    const float* vp = vg + (size_t)(16 * dt + lr) * PLANE;
#pragma unroll
    for (int m = 0; m < 2; ++m) {
      int ka = 4 * lg + 32 * m, kb = ka + 16;
      vA[dt][m] = *(const float4*)(vp + (y0 + (ka >> 3)) * 128 + xw + (ka & 7));
      vB[dt][m] = *(const float4*)(vp + (y0 + (kb >> 3)) * 128 + xw + (kb & 7));
    }
  }
  // K raw (32 scalar): kk[kt][j] = K[8lg+j][16kt+lr]
  float kk[4][8];
#pragma unroll
  for (int kt = 0; kt < 4; ++kt) {
    int kpos = 16 * kt + lr;
    int spk = (y0 + (kpos >> 3)) * 128 + xw + (kpos & 7);
#pragma unroll
    for (int j = 0; j < 8; ++j)
      kk[kt][j] = kg[(size_t)(8 * lg + j) * PLANE + spk];
  }
  // Q raw (32 scalar, all 4 strips): qq[st][j] = Q[8lg+j][16st+lr]
  float qq[4][8];
#pragma unroll
  for (int st = 0; st < 4; ++st) {
    int q = 16 * st + lr;
    int spq = (y0 + (q >> 3)) * 128 + xw + (q & 7);
#pragma unroll
    for (int j = 0; j < 8; ++j)
      qq[st][j] = qg[(size_t)(8 * lg + j) * PLANE + spq];
  }

  // ================= phase 1: chm cooperative (c, row, xq) ====================
  {
    const float* cb = ch + ((size_t)(b * 256)) * PLANE;
    int c = tid >> 5, row = (tid >> 2) & 7, xq = tid & 3;
    const float4* src = (const float4*)(cb + (size_t)c * PLANE
                                        + (y0 + row) * 128 + x0) + xq;
    float4 a = {0.f, 0.f, 0.f, 0.f};
#pragma unroll
    for (int l = 0; l < 8; ++l) {
      float4 tv = src[(size_t)(l * 32) * (PLANE / 4)];
      a.x += tv.x; a.y += tv.y; a.z += tv.z; a.w += tv.w;
    }
    a.x *= 0.125f; a.y *= 0.125f; a.z *= 0.125f; a.w *= 0.125f;
    *(float4*)(chm + 132 * c + 16 * row + 4 * xq) = a;
  }
  __syncthreads();   // barrier 1 (drains all outstanding loads once)

  // ================= phase 2: convert + compute (no barriers) =================
  const float scale = __expf(fminf(lsc[h], LOG100));

  // V*chm frags, sigma-permuted: elem j <- kpos 4lg + (j&3) + 16(j>>2) + 32m
  short8v vf[2][2];
#pragma unroll
  for (int dt = 0; dt < 2; ++dt) {
    const float* cm = chm + 132 * (16 * dt + lr);
#pragma unroll
    for (int m = 0; m < 2; ++m) {
      int ka = 4 * lg + 32 * m, kb = ka + 16;
      f32x4 caf = *(const f32x4*)(cm + 16 * (ka >> 3) + 8 * win + (ka & 7));
      f32x4 cbf = *(const f32x4*)(cm + 16 * (kb >> 3) + 8 * win + (kb & 7));
      float4 va = vA[dt][m], vb = vB[dt][m];
      vf[dt][m][0] = (short)f2bf(va.x * caf[0]);
      vf[dt][m][1] = (short)f2bf(va.y * caf[1]);
      vf[dt][m][2] = (short)f2bf(va.z * caf[2]);
      vf[dt][m][3] = (short)f2bf(va.w * caf[3]);
      vf[dt][m][4] = (short)f2bf(vb.x * cbf[0]);
      vf[dt][m][5] = (short)f2bf(vb.y * cbf[1]);
      vf[dt][m][6] = (short)f2bf(vb.z * cbf[2]);
      vf[dt][m][7] = (short)f2bf(vb.w * cbf[3]);
    }
  }

  // K: per-position l2-norm (reduce across lg groups), normalize, hi/lo split
  short8v khi[4], klo[4];
#pragma unroll
  for (int kt = 0; kt < 4; ++kt) {
    float nr = 0.f;
#pragma unroll
    for (int j = 0; j < 8; ++j) nr = fmaf(kk[kt][j], kk[kt][j], nr);
    nr += __shfl_xor(nr, 16);
    nr += __shfl_xor(nr, 32);
    float iv = 1.f / fmaxf(sqrtf(nr), 1e-12f);
#pragma unroll
    for (int j = 0; j < 8; ++j) {
      float x = kk[kt][j] * iv;
      unsigned short hb = f2bf(x);
      khi[kt][j] = (short)hb;
      klo[kt][j] = (short)f2bf(x - bf2f(hb));
    }
  }

  // 4 q-strips
#pragma unroll
  for (int st = 0; st < 4; ++st) {
    const int q = 16 * st + lr;

    float nrq = 0.f;
#pragma unroll
    for (int j = 0; j < 8; ++j) nrq = fmaf(qq[st][j], qq[st][j], nrq);
    nrq += __shfl_xor(nrq, 16);
    nrq += __shfl_xor(nrq, 32);
    const float fq = scale / fmaxf(sqrtf(nrq), 1e-12f);

    short8v qhi, qlo;
#pragma unroll
    for (int j = 0; j < 8; ++j) {
      float x = qq[st][j] * fq;
      unsigned short hb = f2bf(x);
      qhi[j] = (short)hb;
      qlo[j] = (short)f2bf(x - bf2f(hb));
    }

    // S^T tiles + logits + lane-local softmax (kpos = 16kt + 4lg + r)
    const float4* bq = (const float4*)(biasG + (h << 12) + (q << 6));
    float e[16], mx = -1e30f;
#pragma unroll
    for (int kt = 0; kt < 4; ++kt) {
      f32x4 a = {0.f, 0.f, 0.f, 0.f};
      a = __builtin_amdgcn_mfma_f32_16x16x32_bf16(klo[kt], qhi, a, 0, 0, 0);
      a = __builtin_amdgcn_mfma_f32_16x16x32_bf16(khi[kt], qlo, a, 0, 0, 0);
      a = __builtin_amdgcn_mfma_f32_16x16x32_bf16(khi[kt], qhi, a, 0, 0, 0);
      float4 b4 = bq[4 * kt + lg];
      float bb[4] = {b4.x, b4.y, b4.z, b4.w};
#pragma unroll
      for (int r = 0; r < 4; ++r) {
        float lv = a[r] + bb[r];
        e[4 * kt + r] = lv;
        mx = fmaxf(mx, lv);
      }
    }
    mx = fmaxf(mx, __shfl_xor(mx, 16));
    mx = fmaxf(mx, __shfl_xor(mx, 32));
    float s = 0.f;
#pragma unroll
    for (int i = 0; i < 16; ++i) { e[i] = __expf(e[i] - mx); s += e[i]; }
    s += __shfl_xor(s, 16);
    s += __shfl_xor(s, 32);
    float rl = 1.f / s;

    // P B-frags, sigma-permuted
    short8v pf[2];
#pragma unroll
    for (int m = 0; m < 2; ++m)
#pragma unroll
      for (int j = 0; j < 8; ++j)
        pf[m][j] = (short)f2bf(e[4 * (j >> 2) + 8 * m + (j & 3)]);

    // PV; store to swizzled x_lds: byte = pl*512 + (2c ^ ((pl&7)<<4))
    int pl = ((q >> 3) << 4) + win * 8 + (q & 7);
#pragma unroll
    for (int dt = 0; dt < 2; ++dt) {
      f32x4 o = {0.f, 0.f, 0.f, 0.f};
      o = __builtin_amdgcn_mfma_f32_16x16x32_bf16(vf[dt][0], pf[0], o, 0, 0, 0);
      o = __builtin_amdgcn_mfma_f32_16x16x32_bf16(vf[dt][1], pf[1], o, 0, 0, 0);
      u32x2 ww;
      ww[0] = (unsigned)f2bf(o[0] * rl) | ((unsigned)f2bf(o[1] * rl) << 16);
      ww[1] = (unsigned)f2bf(o[2] * rl) | ((unsigned)f2bf(o[3] * rl) << 16);
      unsigned off = (unsigned)(pl * 512)
                   + (((unsigned)(64 * h + 32 * dt + 8 * lg)) ^ ((unsigned)(pl & 7) << 4));
      *(u32x2*)(smem + off) = ww;
    }
  }
  __syncthreads();   // barrier 2

  // ================= phase 3: projection (wave -> 32 o x 64 p) ===============
  const int ow = wv & 7, ph = wv >> 3;
  f32x4 acc[2][4];
#pragma unroll
  for (int i = 0; i < 2; ++i)
#pragma unroll
    for (int j = 0; j < 4; ++j) acc[i][j] = (f32x4){0.f, 0.f, 0.f, 0.f};

#pragma unroll
  for (int kc = 0; kc < 8; ++kc) {
    short8v wf0 = *(const short8v*)(wbf + (size_t)(32 * ow + lr) * 256 + 32 * kc + 8 * lg);
    short8v wf1 = *(const short8v*)(wbf + (size_t)(32 * ow + 16 + lr) * 256 + 32 * kc + 8 * lg);
    short8v xf[4];
#pragma unroll
    for (int pt = 0; pt < 4; ++pt) {
      int pl = 64 * ph + 16 * pt + lr;
      unsigned off = (unsigned)(pl * 512)
                   + (((unsigned)(64 * kc + 16 * lg)) ^ ((unsigned)(pl & 7) << 4));
      xf[pt] = *(const short8v*)(smem + off);
    }
#pragma unroll
    for (int pt = 0; pt < 4; ++pt) {
      acc[0][pt] = __builtin_amdgcn_mfma_f32_16x16x32_bf16(wf0, xf[pt], acc[0][pt], 0, 0, 0);
      acc[1][pt] = __builtin_amdgcn_mfma_f32_16x16x32_bf16(wf1, xf[pt], acc[1][pt], 0, 0, 0);
    }
  }

#pragma unroll
  for (int ot = 0; ot < 2; ++ot) {
#pragma unroll
    for (int r = 0; r < 4; ++r) {
      int o = 32 * ow + 16 * ot + 4 * lg + r;
      float bv = pb[o];
      float* op = out + ((size_t)(b * 256 + o)) * PLANE;
#pragma unroll
      for (int pt = 0; pt < 4; ++pt)
        op[(y0 + 4 * ph + pt) * 128 + x0 + lr] = acc[ot][pt][r] + bv;
    }
  }
}

extern "C" void kernel_launch(void* const* d_in, const int* in_sizes, int n_in,
                              void* d_out, int out_size, void* d_ws, size_t ws_size,
                              hipStream_t stream) {
  const float* qkv  = (const float*)d_in[0];
  const float* ch   = (const float*)d_in[1];
  const float* lsc  = (const float*)d_in[2];
  const float* btab = (const float*)d_in[3];
  const float* pw   = (const float*)d_in[4];
  const float* pb   = (const float*)d_in[5];
  const int*   ridx = (const int*)d_in[6];
  float* out = (float*)d_out;

  char* ws = (char*)d_ws;
  float*          biasG = (float*)ws;                      // 128 KB
  unsigned short* wbf   = (unsigned short*)(ws + 131072);  // 128 KB

  prep_kernel<<<dim3(256), dim3(256), 0, stream>>>(btab, ridx, pw,
                                                   biasG, (unsigned int*)wbf);
  fused_kernel<<<dim3(512), dim3(1024), 0, stream>>>(qkv, ch, lsc, biasG,
                                                     wbf, pb, out);
}

// Round 7
// 128.358 us; speedup vs baseline: 1.5347x; 1.5347x over previous
//
#include <hip/hip_runtime.h>

// Shapes: B=4, NH=8, DIM=32, WS=8, WA=64, H=W=128, PLANE=16384.
// qkv:(4,8,96,128,128)f32  ch:(4,256,128,128)f32  lsc:(8)  btab:(225,8)
// pw:(256,256)  pb:(256)  ridx:(64,64)i32  out:(4,256,128,128)f32
//
// ws: biasG f32 [8][64][64] @0 (128 KB); wbf bf16 [256][256] @128K (128 KB)

typedef __attribute__((ext_vector_type(8))) short short8v;
typedef __attribute__((ext_vector_type(4))) float f32x4;
typedef __attribute__((ext_vector_type(2))) unsigned int u32x2;

#define PLANE 16384
#define LOG100 4.6051701859880914f

static __device__ __forceinline__ unsigned short f2bf(float x) {
  union { float f; unsigned u; } v; v.f = x;
  unsigned r = v.u + 0x7fff + ((v.u >> 16) & 1);
  return (unsigned short)(r >> 16);
}
static __device__ __forceinline__ float bf2f(unsigned short b) {
  union { unsigned u; float f; } v; v.u = ((unsigned)b) << 16;
  return v.f;
}

__global__ __launch_bounds__(256) void prep_kernel(
    const float* __restrict__ btab, const int* __restrict__ ridx,
    const float* __restrict__ pw, float* __restrict__ biasG,
    unsigned int* __restrict__ wbf)
{
  const int blk = blockIdx.x, tid = threadIdx.x;
  if (blk < 128) {                      // biasG[h][q][k]
    int i = blk * 256 + tid;
    int h = i >> 12, qk = i & 4095;
    biasG[i] = btab[ridx[qk] * 8 + h];
  } else {                              // w -> bf16 packed pairs
    int i = (blk - 128) * 256 + tid;
    wbf[i] = (unsigned)f2bf(pw[2 * i]) | ((unsigned)f2bf(pw[2 * i + 1]) << 16);
  }
}

// block = window-pair (512 blocks, 512 threads = 8 waves, wave = head).
// LDS: 64 KB. chm f32 [32][132] aliased into the front of the swizzled
// x_lds bf16 [128][256] tile (freed by barrier before PV writes).
__global__ __attribute__((amdgpu_flat_work_group_size(512, 512),
                          amdgpu_waves_per_eu(2, 4))) void fused_kernel(
    const float* __restrict__ qkv, const float* __restrict__ ch,
    const float* __restrict__ lsc, const float* __restrict__ biasG,
    const unsigned short* __restrict__ wbf, const float* __restrict__ pb,
    float* __restrict__ out)
{
  __shared__ __align__(16) char smem[65536];
  float* chm = (float*)smem;                 // [32][132] f32 (16,896 B)

  const int tid = threadIdx.x;
  int bid = blockIdx.x;
  bid = (bid & 7) * 64 + (bid >> 3);         // XCD swizzle (512 = 8*64)
  const int b   = bid >> 7;
  const int wy  = (bid >> 3) & 15;
  const int wxp = bid & 7;
  const int y0  = wy << 3, x0 = wxp << 4;

  const int h = tid >> 6, lane = tid & 63;
  const int lg = lane >> 4, lr = lane & 15;

  // ---- phase 1: chm[c][pl] = mean over 8 helper layers (coalesced float4)
  {
    const float* cb = ch + ((size_t)(b * 256)) * PLANE;
#pragma unroll
    for (int t = 0; t < 2; ++t) {
      int idx = tid + t * 512;               // (c, row, xq): 32*8*4 = 1024
      int c = idx >> 5, row = (idx >> 2) & 7, xq = idx & 3;
      const float4* src = (const float4*)(cb + (size_t)c * PLANE
                                          + (y0 + row) * 128 + x0) + xq;
      float4 a = {0.f, 0.f, 0.f, 0.f};
#pragma unroll
      for (int l = 0; l < 8; ++l) {
        float4 tv = src[(size_t)(l * 32) * (PLANE / 4)];
        a.x += tv.x; a.y += tv.y; a.z += tv.z; a.w += tv.w;
      }
      a.x *= 0.125f; a.y *= 0.125f; a.z *= 0.125f; a.w *= 0.125f;
      *(float4*)(chm + 132 * c + 16 * row + 4 * xq) = a;
    }
  }
  __syncthreads();

  const size_t qbase = ((size_t)((b * 8 + h) * 96)) * PLANE;
  const float* qg = qkv + qbase;
  const float* kg = qg + (size_t)32 * PLANE;
  const float* vg = qg + (size_t)64 * PLANE;
  const float scale = __expf(fminf(lsc[h], LOG100));

  // ---- V*chm frags, BOTH windows (chm dies after this phase).
  // sigma-permutation: elem j <- window kpos 4*lg + (j&3) + 16*(j>>2) + 32*m
  short8v vf[2][2][2];
#pragma unroll
  for (int win = 0; win < 2; ++win) {
    const int xw = x0 + win * 8;
#pragma unroll
    for (int dt = 0; dt < 2; ++dt) {
      const int d = 16 * dt + lr;
      const float* vp = vg + (size_t)d * PLANE;
      const float* cm = chm + 132 * d;
#pragma unroll
      for (int m = 0; m < 2; ++m) {
        int ka = 4 * lg + 32 * m, kb2 = ka + 16;
        int ra = ka >> 3, ca = ka & 7, rb = kb2 >> 3, cb2 = kb2 & 7;
        float4 va  = *(const float4*)(vp + (y0 + ra) * 128 + xw + ca);
        float4 vb  = *(const float4*)(vp + (y0 + rb) * 128 + xw + cb2);
        f32x4 caf = *(const f32x4*)(cm + 16 * ra + 8 * win + ca);
        f32x4 cbf = *(const f32x4*)(cm + 16 * rb + 8 * win + cb2);
        vf[win][dt][m][0] = (short)f2bf(va.x * caf[0]);
        vf[win][dt][m][1] = (short)f2bf(va.y * caf[1]);
        vf[win][dt][m][2] = (short)f2bf(va.z * caf[2]);
        vf[win][dt][m][3] = (short)f2bf(va.w * caf[3]);
        vf[win][dt][m][4] = (short)f2bf(vb.x * cbf[0]);
        vf[win][dt][m][5] = (short)f2bf(vb.y * cbf[1]);
        vf[win][dt][m][6] = (short)f2bf(vb.z * cbf[2]);
        vf[win][dt][m][7] = (short)f2bf(vb.w * cbf[3]);
      }
    }
  }
  __syncthreads();   // chm region now reusable as x_lds

  const float* bgh = biasG + (h << 12);

  // ---- attention per window; x written bf16 to swizzled x_lds[128][256]
#pragma unroll 1
  for (int win = 0; win < 2; ++win) {
    const int xw = x0 + win * 8;

    // issue ALL Q loads for the 4 strips of this window up front (32 dwords)
    float qq[4][8];
#pragma unroll
    for (int st = 0; st < 4; ++st) {
      int q = 16 * st + lr;
      int spq = (y0 + (q >> 3)) * 128 + xw + (q & 7);
#pragma unroll
      for (int j = 0; j < 8; ++j)
        qq[st][j] = qg[(size_t)(8 * lg + j) * PLANE + spq];
    }

    // K raw loads (32 dwords), then per-position norm + hi/lo split
    float kk[4][8];
#pragma unroll
    for (int kt = 0; kt < 4; ++kt) {
      int kpos = 16 * kt + lr;
      int spk = (y0 + (kpos >> 3)) * 128 + xw + (kpos & 7);
#pragma unroll
      for (int j = 0; j < 8; ++j)
        kk[kt][j] = kg[(size_t)(8 * lg + j) * PLANE + spk];
    }

    short8v khi[4], klo[4];
#pragma unroll
    for (int kt = 0; kt < 4; ++kt) {
      float nr = 0.f;
#pragma unroll
      for (int j = 0; j < 8; ++j) nr = fmaf(kk[kt][j], kk[kt][j], nr);
      nr += __shfl_xor(nr, 16);
      nr += __shfl_xor(nr, 32);
      float iv = 1.f / fmaxf(sqrtf(nr), 1e-12f);
#pragma unroll
      for (int j = 0; j < 8; ++j) {
        float x = kk[kt][j] * iv;
        unsigned short hb = f2bf(x);
        khi[kt][j] = (short)hb;
        klo[kt][j] = (short)f2bf(x - bf2f(hb));
      }
    }

    // 4 q-strips (Q already resident)
#pragma unroll 1
    for (int st = 0; st < 4; ++st) {
      int q = 16 * st + lr;
      float nrq = 0.f;
#pragma unroll
      for (int j = 0; j < 8; ++j) nrq = fmaf(qq[st][j], qq[st][j], nrq);
      nrq += __shfl_xor(nrq, 16);
      nrq += __shfl_xor(nrq, 32);
      const float fq = scale / fmaxf(sqrtf(nrq), 1e-12f);

      short8v qhi, qlo;
#pragma unroll
      for (int j = 0; j < 8; ++j) {
        float x = qq[st][j] * fq;
        unsigned short hb = f2bf(x);
        qhi[j] = (short)hb;
        qlo[j] = (short)f2bf(x - bf2f(hb));
      }

      // S^T tiles + logits + lane-local softmax (kpos = 16*kt + 4*lg + r)
      const float4* bq = (const float4*)(bgh + (q << 6));
      float e[16], mx = -1e30f;
#pragma unroll
      for (int kt = 0; kt < 4; ++kt) {
        f32x4 a = {0.f, 0.f, 0.f, 0.f};
        a = __builtin_amdgcn_mfma_f32_16x16x32_bf16(klo[kt], qhi, a, 0, 0, 0);
        a = __builtin_amdgcn_mfma_f32_16x16x32_bf16(khi[kt], qlo, a, 0, 0, 0);
        a = __builtin_amdgcn_mfma_f32_16x16x32_bf16(khi[kt], qhi, a, 0, 0, 0);
        float4 b4 = bq[4 * kt + lg];
        float bb[4] = {b4.x, b4.y, b4.z, b4.w};
#pragma unroll
        for (int r = 0; r < 4; ++r) {
          float lv = a[r] + bb[r];
          e[4 * kt + r] = lv;
          mx = fmaxf(mx, lv);
        }
      }
      mx = fmaxf(mx, __shfl_xor(mx, 16));
      mx = fmaxf(mx, __shfl_xor(mx, 32));
      float s = 0.f;
#pragma unroll
      for (int i = 0; i < 16; ++i) { e[i] = __expf(e[i] - mx); s += e[i]; }
      s += __shfl_xor(s, 16);
      s += __shfl_xor(s, 32);
      float rl = 1.f / s;

      // P B-frags, sigma-permuted
      short8v pf[2];
#pragma unroll
      for (int m = 0; m < 2; ++m)
#pragma unroll
        for (int j = 0; j < 8; ++j)
          pf[m][j] = (short)f2bf(e[4 * (j >> 2) + 8 * m + (j & 3)]);

      // PV; store to swizzled x_lds: byte = pl*512 + (2c ^ ((pl&7)<<4))
      int pl = ((q >> 3) << 4) + win * 8 + (q & 7);
#pragma unroll
      for (int dt = 0; dt < 2; ++dt) {
        f32x4 o = {0.f, 0.f, 0.f, 0.f};
        o = __builtin_amdgcn_mfma_f32_16x16x32_bf16(vf[win][dt][0], pf[0], o, 0, 0, 0);
        o = __builtin_amdgcn_mfma_f32_16x16x32_bf16(vf[win][dt][1], pf[1], o, 0, 0, 0);
        u32x2 ww;
        ww[0] = (unsigned)f2bf(o[0] * rl) | ((unsigned)f2bf(o[1] * rl) << 16);
        ww[1] = (unsigned)f2bf(o[2] * rl) | ((unsigned)f2bf(o[3] * rl) << 16);
        unsigned off = (unsigned)(pl * 512)
                     + (((unsigned)(64 * h + 32 * dt + 8 * lg)) ^ ((unsigned)(pl & 7) << 4));
        *(u32x2*)(smem + off) = ww;
      }
    }
  }
  __syncthreads();

  // ---- projection: wave h computes o in [32h, 32h+32) x 128 positions
  f32x4 acc[2][8];
#pragma unroll
  for (int i = 0; i < 2; ++i)
#pragma unroll
    for (int j = 0; j < 8; ++j) acc[i][j] = (f32x4){0.f, 0.f, 0.f, 0.f};

#pragma unroll 1
  for (int kc = 0; kc < 8; ++kc) {
    short8v wf0 = *(const short8v*)(wbf + (size_t)(32 * h + lr) * 256 + 32 * kc + 8 * lg);
    short8v wf1 = *(const short8v*)(wbf + (size_t)(32 * h + 16 + lr) * 256 + 32 * kc + 8 * lg);
    short8v xf[8];
#pragma unroll
    for (int pt = 0; pt < 8; ++pt) {
      int pl = 16 * pt + lr;
      unsigned off = (unsigned)(pl * 512)
                   + (((unsigned)(64 * kc + 16 * lg)) ^ ((unsigned)(pl & 7) << 4));
      xf[pt] = *(const short8v*)(smem + off);
    }
#pragma unroll
    for (int pt = 0; pt < 8; ++pt) {
      acc[0][pt] = __builtin_amdgcn_mfma_f32_16x16x32_bf16(wf0, xf[pt], acc[0][pt], 0, 0, 0);
      acc[1][pt] = __builtin_amdgcn_mfma_f32_16x16x32_bf16(wf1, xf[pt], acc[1][pt], 0, 0, 0);
    }
  }

#pragma unroll
  for (int ot = 0; ot < 2; ++ot) {
#pragma unroll
    for (int r = 0; r < 4; ++r) {
      int o = 32 * h + 16 * ot + 4 * lg + r;
      float bv = pb[o];
      float* op = out + ((size_t)(b * 256 + o)) * PLANE;
#pragma unroll
      for (int pt = 0; pt < 8; ++pt)
        op[(y0 + pt) * 128 + x0 + lr] = acc[ot][pt][r] + bv;
    }
  }
}

extern "C" void kernel_launch(void* const* d_in, const int* in_sizes, int n_in,
                              void* d_out, int out_size, void* d_ws, size_t ws_size,
                              hipStream_t stream) {
  const float* qkv  = (const float*)d_in[0];
  const float* ch   = (const float*)d_in[1];
  const float* lsc  = (const float*)d_in[2];
  const float* btab = (const float*)d_in[3];
  const float* pw   = (const float*)d_in[4];
  const float* pb   = (const float*)d_in[5];
  const int*   ridx = (const int*)d_in[6];
  float* out = (float*)d_out;

  char* ws = (char*)d_ws;
  float*          biasG = (float*)ws;                      // 128 KB
  unsigned short* wbf   = (unsigned short*)(ws + 131072);  // 128 KB

  prep_kernel<<<dim3(256), dim3(256), 0, stream>>>(btab, ridx, pw,
                                                   biasG, (unsigned int*)wbf);
  fused_kernel<<<dim3(512), dim3(512), 0, stream>>>(qkv, ch, lsc, biasG,
                                                    wbf, pb, out);
}